// Round 5
// baseline (74.116 us; speedup 1.0000x reference)
//
#include <hip/hip_runtime.h>

// out[b,m,n,p] = proj0[b,m] * proj1[b,n] * proj2[m,p]
// proj_j[b,o] = sum_i x[b,i] * w[o,i,j],  x:(96,3) w:(96,3,8)  w[o,i,j] at o*24+i*8+j
// Second matmul's batch broadcast aligns proj2's batch dim with m (not b).

#define NB 96
#define MG 4                    // m-values per block
#define GROUPS (NB / MG)        // 24  -> grid 96*24 = 2304 = 9 blocks/CU exactly

typedef float f32x4 __attribute__((ext_vector_type(4)));

__global__ __launch_bounds__(256) void nckart_kernel(
    const float* __restrict__ x,   // [96,3]
    const float* __restrict__ w,   // [96,3,8]
    float* __restrict__ out)       // [96,96,96,96] flat
{
    const int blk = blockIdx.x;          // 0..2303
    const int b   = blk / GROUPS;
    const int m0  = (blk % GROUPS) * MG;
    const int t   = threadIdx.x;

    __shared__ float p1[NB];             // proj1[b, n]
    __shared__ float sp[MG][NB];         // proj0[b,m0+ml] * proj2[m0+ml, p]

    const float xb0 = x[b*3 + 0], xb1 = x[b*3 + 1], xb2 = x[b*3 + 2];

    if (t < NB) {
        p1[t] = xb0 * w[t*24 + 1] + xb1 * w[t*24 + 9] + xb2 * w[t*24 + 17];
    }
    // 384 sp entries, 256 threads -> <=2 each
    for (int e = t; e < MG * NB; e += 256) {
        const int ml = e / NB;
        const int p  = e % NB;
        const int m  = m0 + ml;
        const float s  = xb0 * w[m*24 + 0] + xb1 * w[m*24 + 8] + xb2 * w[m*24 + 16];
        const float p2 = x[m*3 + 0] * w[p*24 + 2]
                       + x[m*3 + 1] * w[p*24 + 10]
                       + x[m*3 + 2] * w[p*24 + 18];
        sp[ml][p] = s * p2;
    }
    __syncthreads();

    // Contiguous output region for this block: 4 * 96 * 96 floats = 144 KB.
    f32x4* out4 = reinterpret_cast<f32x4*>(out) + (size_t)(b * NB + m0) * (NB * NB / 4);

    #pragma unroll
    for (int ml = 0; ml < MG; ++ml) {
        const f32x4* sp4 = reinterpret_cast<const f32x4*>(sp[ml]);
        f32x4* o4 = out4 + (size_t)ml * (NB * NB / 4);
        #pragma unroll
        for (int it = 0; it < 9; ++it) {
            const int idx = t + it * 256;    // 0..2303 float4 slots in this m-tile
            const int n   = idx / 24;
            const int p4  = idx % 24;
            f32x4 v = sp4[p4];
            const float a = p1[n];
            v *= a;
            __builtin_nontemporal_store(v, &o4[idx]);
        }
    }
}

extern "C" void kernel_launch(void* const* d_in, const int* in_sizes, int n_in,
                              void* d_out, int out_size, void* d_ws, size_t ws_size,
                              hipStream_t stream) {
    const float* x = (const float*)d_in[0];
    const float* w = (const float*)d_in[1];
    float* out = (float*)d_out;

    nckart_kernel<<<NB * GROUPS, 256, 0, stream>>>(x, w, out);
}

// Round 6
// 69.491 us; speedup vs baseline: 1.0666x; 1.0666x over previous
//
#include <hip/hip_runtime.h>

// out[b,m,n,p] = s[b,m] * p1[b,n] * q[m,p]
//   s[b,m]  = sum_i x[b,i]*w[m,i,0]
//   p1[b,n] = sum_i x[b,i]*w[n,i,1]
//   q[m,p]  = sum_i x[m,i]*w[p,i,2]   (second matmul broadcasts over m, not b)
// Two-kernel split: prep writes the 3 factor tables to ws; main kernel is a
// pure store stream (no LDS, no __syncthreads) to mimic fillBufferAligned.

#define NB 96
#define TBL (NB * NB)          // 9216

typedef float f32x4 __attribute__((ext_vector_type(4)));

__global__ __launch_bounds__(256) void prep_kernel(
    const float* __restrict__ x,   // [96,3]
    const float* __restrict__ w,   // [96,3,8]  w[o,i,j] at o*24+i*8+j
    float* __restrict__ ws)        // [3*9216]: s | p1 | q
{
    const int v = blockIdx.x * 256 + threadIdx.x;   // 0..27647
    if (v >= 3 * TBL) return;
    const int which = v / TBL;       // 0=s, 1=p1, 2=q
    const int r     = v % TBL;
    const int a     = r / NB;        // b (s,p1) or m (q)
    const int c     = r % NB;        // m, n, or p
    const float x0 = x[a*3 + 0], x1 = x[a*3 + 1], x2 = x[a*3 + 2];
    const int j = which;             // spline column 0,1,2
    ws[v] = x0 * w[c*24 + 0*8 + j] + x1 * w[c*24 + 1*8 + j] + x2 * w[c*24 + 2*8 + j];
}

__global__ __launch_bounds__(256) void nckart_store(
    const float* __restrict__ ws,  // s | p1 | q
    float* __restrict__ out)       // [96,96,96,96]
{
    const int bm = blockIdx.x;     // 0..9215
    const int b  = bm / NB;
    const int m  = bm % NB;
    const int t  = threadIdx.x;

    const float*  s  = ws;
    const float*  p1 = ws + TBL;
    const f32x4*  q4 = reinterpret_cast<const f32x4*>(ws + 2 * TBL);

    const float A = s[bm];
    f32x4* o4 = reinterpret_cast<f32x4*>(out) + (size_t)bm * (NB * NB / 4);

    #pragma unroll
    for (int it = 0; it < 9; ++it) {
        const int idx = t + it * 256;        // 0..2303
        const int n   = idx / 24;
        const int p4  = idx % 24;
        f32x4 v = q4[m * 24 + p4];
        v *= (A * p1[b * NB + n]);
        o4[idx] = v;
    }
}

extern "C" void kernel_launch(void* const* d_in, const int* in_sizes, int n_in,
                              void* d_out, int out_size, void* d_ws, size_t ws_size,
                              hipStream_t stream) {
    const float* x = (const float*)d_in[0];
    const float* w = (const float*)d_in[1];
    float* out = (float*)d_out;
    float* ws  = (float*)d_ws;

    prep_kernel<<<(3 * TBL + 255) / 256, 256, 0, stream>>>(x, w, ws);
    nckart_store<<<TBL, 256, 0, stream>>>(ws, out);
}